// Round 8
// baseline (155.614 us; speedup 1.0000x reference)
//
#include <hip/hip_runtime.h>
#include <math.h>

// Tiles: B*NTH*NTW = 64*56*56
constexpr int TT = 64 * 56 * 56;   // 200704 == 3136 * 64
// M = 8 slots, DF = 8 flux dims, output row = 2 + 8 + 1 = 11 floats
// out per tile = 88 floats = 22 float4.

// ---------------------------------------------------------------------------
// Kernel A: dense per-tile matching (1 thread = 1 tile, all 64 lanes busy).
// Emits packed rowsrc word: 4 bits per output row r = (8|j) if row r takes
// true row j, else 0.
// ---------------------------------------------------------------------------
__global__ __launch_bounds__(64) void mvd_match_only(
    const float4* __restrict__ el4,   // est_locs  [TT*4] float4
    const float4* __restrict__ tl4,   // true_locs [TT*4] float4
    const int*    __restrict__ en_,
    const int*    __restrict__ tn_,
    int*          __restrict__ match) // [TT]
{
#pragma clang fp contract(off)
    const int t = blockIdx.x * 64 + threadIdx.x;

    const int en = en_[t];
    const int tn = tn_[t];

    float4 ea = el4[t * 4 + 0], eb = el4[t * 4 + 1];
    float4 ec = el4[t * 4 + 2], ed = el4[t * 4 + 3];
    float4 ta = tl4[t * 4 + 0], tb = tl4[t * 4 + 1];
    float4 tc = tl4[t * 4 + 2], td = tl4[t * 4 + 3];

    float mex[8], mey[8], mtx[8], mty[8];
    {
        const float exs[8] = {ea.x, ea.z, eb.x, eb.z, ec.x, ec.z, ed.x, ed.z};
        const float eys[8] = {ea.y, ea.w, eb.y, eb.w, ec.y, ec.w, ed.y, ed.w};
        const float txs[8] = {ta.x, ta.z, tb.x, tb.z, tc.x, tc.z, td.x, td.z};
        const float tys[8] = {ta.y, ta.w, tb.y, tb.w, tc.y, tc.w, td.y, td.w};
#pragma unroll
        for (int i = 0; i < 8; i++) {
            mex[i] = (i < en) ? exs[i] : 100.0f;
            mey[i] = (i < en) ? eys[i] : 100.0f;
            mtx[i] = (i < tn) ? txs[i] : 100.0f;
            mty[i] = (i < tn) ? tys[i] : 100.0f;
        }
    }

    // sqrt REQUIRED: fp32 sqrt rounding can merge values distinct in squared
    // form; numpy argmin tie-breaks to the earlier index on the rounded
    // values. Default HIP sqrtf is IEEE == np.sqrt bitwise.
    // Strict '<' + ascending index == numpy first-occurrence argmin.
    float colmin[8];
    int   m1[8], m2[8];
#pragma unroll
    for (int j = 0; j < 8; j++) { colmin[j] = 1e30f; m1[j] = 0; }
#pragma unroll
    for (int i = 0; i < 8; i++) {
        float rmin = 1e30f;
        int   rj = 0;
#pragma unroll
        for (int j = 0; j < 8; j++) {
            float dx = mex[i] - mtx[j];
            float dy = mey[i] - mty[j];
            float dx2 = dx * dx;
            float dy2 = dy * dy;
            float d = sqrtf(dx2 + dy2);
            if (d < rmin) { rmin = d; rj = j; }
            if (d < colmin[j]) { colmin[j] = d; m1[j] = i; }
        }
        m2[i] = rj;
    }

    int m1p = 0;
#pragma unroll
    for (int j = 0; j < 8; j++) m1p |= m1[j] << (3 * j);

    // one2one + scatter (ascending k, last-wins == numpy fancy assignment)
    int rowsrc = 0;
#pragma unroll
    for (int k = 0; k < 8; k++) {
        int j = m2[k];
        int m1j = (m1p >> (3 * j)) & 7;
        bool o2o = (m1j == k) && (m1[k] < en) && (m2[k] < tn);
        if (o2o) {
            int r = m1[k];
            rowsrc = (rowsrc & ~(0xF << (4 * r))) | ((8 | j) << (4 * r));
        }
    }
    match[t] = rowsrc;
}

// ---------------------------------------------------------------------------
// Kernel B: one thread per output float4 (TT*22 = 4.4M threads, 69k waves —
// enough TLP to hide all gather latency). BRANCHLESS loads: both candidate
// addresses computed in-bounds, pointer selected via cndmask, single
// unconditional global_load_dword per element; result masked afterwards.
// The rounds 2-7 plateau (~50 µs) was exec-masked per-element loads
// serializing into a per-wave latency chain with only 3136 waves to hide it.
// Matched rows always have indicator 1.0 (one2one implies match2[k] < tn).
// ---------------------------------------------------------------------------
__global__ __launch_bounds__(256) void mvd_write_flat(
    const float*  __restrict__ tl,    // true_locs  [TT*16]
    const float*  __restrict__ tf,    // true_fluxes [TT*64]
    const int*    __restrict__ match, // [TT]
    float4*       __restrict__ out4)  // [TT*22]
{
    const int idx = blockIdx.x * 256 + threadIdx.x;  // output float4 index
    const int t = idx / 22;           // magic-mul (constant divisor)
    const int q = idx - t * 22;
    const int w = match[t];           // 22 adjacent lanes share -> L1 hit

    float res[4];
#pragma unroll
    for (int u = 0; u < 4; u++) {
        const int p = 4 * q + u;            // 0..87 within tile
        const int r = (p * 94) >> 10;       // == p/11 for p in [0,88)
        const int c = p - r * 11;
        const int v = (w >> (4 * r)) & 15;
        const int j = v & 7;                // 0 when unmatched (safe)

        // candidate addresses, both always in-bounds:
        //   tl: c&1 == c when c<2 (the only case this pointer is selected)
        //   tf: min(c-2,7) keeps j=7,c=10 inside tile t
        const float* pa = tl + ((t << 4) + (j << 1) + (c & 1));
        const int ct = (c > 9) ? 7 : (c - 2);     // c>=2 when selected
        const float* pb = tf + ((t << 6) + (j << 3) + ct);
        const float* pr = (c < 2) ? pa : pb;      // v_cndmask on address
        const float val = *pr;                    // unconditional load

        const float sel = (c == 10) ? 1.0f : val;
        res[u] = (v & 8) ? sel : 0.0f;
    }
    out4[idx] = make_float4(res[0], res[1], res[2], res[3]);
}

extern "C" void kernel_launch(void* const* d_in, const int* in_sizes, int n_in,
                              void* d_out, int out_size, void* d_ws, size_t ws_size,
                              hipStream_t stream) {
    const float* est_locs    = (const float*)d_in[0];
    const float* true_locs   = (const float*)d_in[1];
    const float* true_fluxes = (const float*)d_in[2];
    const int*   est_n       = (const int*)d_in[3];
    const int*   true_n      = (const int*)d_in[4];
    float* out = (float*)d_out;

    int* match = (int*)d_ws;   // TT*4 = 0.8 MB, ws is far larger

    mvd_match_only<<<TT / 64, 64, 0, stream>>>(
        (const float4*)est_locs, (const float4*)true_locs,
        est_n, true_n, match);

    mvd_write_flat<<<(TT * 22) / 256, 256, 0, stream>>>(
        true_locs, true_fluxes, match, (float4*)out);
}

// Round 9
// 150.589 us; speedup vs baseline: 1.0334x; 1.0334x over previous
//
#include <hip/hip_runtime.h>
#include <math.h>

// Tiles: B*NTH*NTW = 64*56*56
constexpr int TT = 64 * 56 * 56;   // 200704 == 3136 * 64
// M = 8 slots, DF = 8 flux dims, output row = 2 + 8 + 1 = 11 floats
// out per tile = 88 floats = 22 float4.
//
// One block = 1 wave = 64 tiles, single launch, no LDS, no workspace.
// Phase 1: dense matching — thread i matches tile t0+i (all 64 lanes busy;
//   R4 showed lane-sparse matching waves cost 5x).
// Phase 2: 22 coalesced float4 stores/thread. Gathers are BRANCHLESS:
//   both candidate addresses computed, pointer picked with v_cndmask,
//   ONE unconditional global_load_dword per element, result masked after.
//   (R6's exec-masked per-element branches made an unhidable per-wave
//   latency chain — the 50 µs plateau of rounds 2-7.)
//   Unmatched / indicator lanes redirect to the tile's tl base line (already
//   fetched) so no extra flux cache lines are pulled.
//   rowsrc crosses phases via __shfl, not LDS.
__global__ __launch_bounds__(64) void mvd_fused_branchless(
    const float4* __restrict__ el4,   // est_locs  [TT*4] float4
    const float4* __restrict__ tl4,   // true_locs [TT*4] float4
    const float*  __restrict__ tf,    // true_fluxes [TT*64]
    const int*    __restrict__ en_,
    const int*    __restrict__ tn_,
    float4*       __restrict__ out4)  // [TT*22]
{
#pragma clang fp contract(off)
    const int lane = threadIdx.x;
    const int t0   = blockIdx.x * 64;
    const int t    = t0 + lane;

    // ---------------- Phase 1: dense per-thread matching ----------------
    int rowsrc = 0;
    {
        const int en = en_[t];
        const int tn = tn_[t];

        float4 ea = el4[t * 4 + 0], eb = el4[t * 4 + 1];
        float4 ec = el4[t * 4 + 2], ed = el4[t * 4 + 3];
        float4 ta = tl4[t * 4 + 0], tb = tl4[t * 4 + 1];
        float4 tc = tl4[t * 4 + 2], td = tl4[t * 4 + 3];

        float mex[8], mey[8], mtx[8], mty[8];
        {
            const float exs[8] = {ea.x, ea.z, eb.x, eb.z, ec.x, ec.z, ed.x, ed.z};
            const float eys[8] = {ea.y, ea.w, eb.y, eb.w, ec.y, ec.w, ed.y, ed.w};
            const float txs[8] = {ta.x, ta.z, tb.x, tb.z, tc.x, tc.z, td.x, td.z};
            const float tys[8] = {ta.y, ta.w, tb.y, tb.w, tc.y, tc.w, td.y, td.w};
#pragma unroll
            for (int i = 0; i < 8; i++) {
                mex[i] = (i < en) ? exs[i] : 100.0f;
                mey[i] = (i < en) ? eys[i] : 100.0f;
                mtx[i] = (i < tn) ? txs[i] : 100.0f;
                mty[i] = (i < tn) ? tys[i] : 100.0f;
            }
        }

        // sqrt REQUIRED: fp32 sqrt rounding can merge values distinct in
        // squared form; numpy argmin tie-breaks to the earlier index on the
        // rounded values. Default HIP sqrtf is IEEE == np.sqrt bitwise.
        // Strict '<' + ascending index == numpy first-occurrence argmin.
        float colmin[8];
        int   m1[8], m2[8];
#pragma unroll
        for (int j = 0; j < 8; j++) { colmin[j] = 1e30f; m1[j] = 0; }
#pragma unroll
        for (int i = 0; i < 8; i++) {
            float rmin = 1e30f;
            int   rj = 0;
#pragma unroll
            for (int j = 0; j < 8; j++) {
                float dx = mex[i] - mtx[j];
                float dy = mey[i] - mty[j];
                float dx2 = dx * dx;
                float dy2 = dy * dy;
                float d = sqrtf(dx2 + dy2);
                if (d < rmin) { rmin = d; rj = j; }
                if (d < colmin[j]) { colmin[j] = d; m1[j] = i; }
            }
            m2[i] = rj;
        }

        int m1p = 0;
#pragma unroll
        for (int j = 0; j < 8; j++) m1p |= m1[j] << (3 * j);

        // one2one + scatter (ascending k, last-wins == numpy fancy assign)
        // rowsrc: 4 bits per output row r: (8|j) if matched from true row j
#pragma unroll
        for (int k = 0; k < 8; k++) {
            int j = m2[k];
            int m1j = (m1p >> (3 * j)) & 7;
            bool o2o = (m1j == k) && (m1[k] < en) && (m2[k] < tn);
            if (o2o) {
                int r = m1[k];
                rowsrc = (rowsrc & ~(0xF << (4 * r))) | ((8 | j) << (4 * r));
            }
        }
    }

    // -------- Phase 2: coalesced stores, branchless global gathers --------
    const float* tl = (const float*)tl4;
    float4* oblk = out4 + (size_t)t0 * 22;

#pragma unroll
    for (int it = 0; it < 22; it++) {
        const int i   = lane + it * 64;          // 0..1407 float4 in block
        const int tl_ = (i * 2979) >> 16;        // == i/22 for i < 1408
        const int q   = i - tl_ * 22;
        const int w   = __shfl(rowsrc, tl_);     // tile tl_'s match word
        const int tt  = t0 + tl_;

        float res[4];
#pragma unroll
        for (int u = 0; u < 4; u++) {
            const int p = 4 * q + u;             // 0..87 within tile
            const int r = (p * 94) >> 10;        // == p/11 for p < 88
            const int c = p - r * 11;
            const int v = (w >> (4 * r)) & 15;
            const int j = v & 7;
            const bool matched = (v & 8) != 0;

            // candidate addresses (computed unconditionally; OOB candidates
            // are never dereferenced — final select redirects them):
            const float* ptl = tl + ((tt << 4) + (j << 1) + (c & 1));
            const float* ptf = tf + ((tt << 6) + (j << 3) + (c - 2));
            const float* pr  = (c < 2) ? ptl : ptf;          // cndmask
            // unmatched or indicator lanes -> tile's tl base (line already
            // needed by other lanes; avoids fetching unmatched flux lines)
            pr = (matched && c < 10) ? pr : (tl + (tt << 4)); // cndmask
            const float val = *pr;                            // one load

            const float sel = (c == 10) ? 1.0f : val;
            res[u] = matched ? sel : 0.0f;
        }
        oblk[i] = make_float4(res[0], res[1], res[2], res[3]);
    }
}

extern "C" void kernel_launch(void* const* d_in, const int* in_sizes, int n_in,
                              void* d_out, int out_size, void* d_ws, size_t ws_size,
                              hipStream_t stream) {
    const float* est_locs    = (const float*)d_in[0];
    const float* true_locs   = (const float*)d_in[1];
    const float* true_fluxes = (const float*)d_in[2];
    const int*   est_n       = (const int*)d_in[3];
    const int*   true_n      = (const int*)d_in[4];
    float* out = (float*)d_out;

    mvd_fused_branchless<<<TT / 64, 64, 0, stream>>>(
        (const float4*)est_locs, (const float4*)true_locs, true_fluxes,
        est_n, true_n, (float4*)out);
}

// Round 10
// 128.859 us; speedup vs baseline: 1.2076x; 1.1686x over previous
//
#include <hip/hip_runtime.h>
#include <math.h>

// Tiles: B*NTH*NTW = 64*56*56
constexpr int TT = 64 * 56 * 56;   // 200704 == 6272 * 32
// M = 8 slots, DF = 8 flux dims, output row = 11 floats; tile = 88 floats.
//
// R2..R9 all plateaued at ~51 µs with one-THREAD-per-tile (3136 waves =
// 12.25/CU — stall chains can't overlap). This kernel uses 8 LANES per tile:
// lane L of a wave = (tile L>>3, row L&7). 25088 waves (8x TLP), coalesced
// float2 loc loads, cross-lane matching via shuffles/ballot, 3 wide
// exec-masked row gathers, LDS assembly (contiguous == output layout),
// 3 coalesced dwordx4 stores per wave.
__global__ __launch_bounds__(256) void mvd_coop(
    const float2* __restrict__ el2,   // est_locs  [TT*8] float2 rows
    const float2* __restrict__ tl2,   // true_locs [TT*8] float2 rows
    const float4* __restrict__ tf4,   // true_fluxes [TT*16] float4
    const int*    __restrict__ en_,
    const int*    __restrict__ tn_,
    float4*       __restrict__ out4)  // [TT*22]
{
#pragma clang fp contract(off)
    const int w    = threadIdx.x >> 6;      // wave in block (0..3)
    const int L    = threadIdx.x & 63;      // lane
    const int tloc = L >> 3;                // tile within wave (0..7)
    const int r    = L & 7;                 // row within tile
    const int tb   = blockIdx.x * 32 + w * 8;   // wave's first tile
    const int gt   = tb + tloc;             // this lane's tile
    const int g    = gt * 8 + r;            // this lane's global row

    __shared__ float s_buf[4][704];         // 8 tiles * 88 floats per wave
    float* sw = s_buf[w];

    const int en = en_[gt];
    const int tn = tn_[gt];

    const float2 eL = el2[g];               // coalesced (permuted range)
    const float2 tL = tl2[g];

    // masked values exactly as numpy builds them (FAR=100 sentinel)
    const float ex = (r < en) ? eL.x : 100.0f;
    const float ey = (r < en) ? eL.y : 100.0f;
    const float tx = (r < tn) ? tL.x : 100.0f;
    const float ty = (r < tn) ? tL.y : 100.0f;

    // d[j] = dist(est row r, true col j). Same op order as numpy
    // (contract off) + IEEE sqrtf == np.sqrt bitwise (ties must match:
    // sqrt rounding can merge squared-distinct values).
    float d[8];
#pragma unroll
    for (int j = 0; j < 8; j++) {
        const float txj = __shfl(tx, j, 8);
        const float tyj = __shfl(ty, j, 8);
        const float dx = ex - txj;
        const float dy = ey - tyj;
        const float dx2 = dx * dx;
        const float dy2 = dy * dy;
        d[j] = sqrtf(dx2 + dy2);
    }

    // m2 (own est row): argmin_j, strict '<' ascending == numpy first-occ.
    float rmin = 1e30f; int m2o = 0;
#pragma unroll
    for (int j = 0; j < 8; j++)
        if (d[j] < rmin) { rmin = d[j]; m2o = j; }

    // m1[j] = argmin over rows (first occurrence): 3-step min butterfly
    // within the 8-lane group, then ballot + ffs picks the smallest row
    // holding the min (== numpy tie-break).
    const int gbase = L & 56;
    int m1p = 0;
#pragma unroll
    for (int j = 0; j < 8; j++) {
        float dm = d[j];
#pragma unroll
        for (int s = 1; s < 8; s <<= 1) {
            const float o = __shfl_xor(dm, s);
            dm = (o < dm) ? o : dm;
        }
        const unsigned long long bal = __ballot(d[j] == dm);
        const int b = (int)((bal >> gbase) & 0xFFull);   // nonzero
        m1p |= (__ffs(b) - 1) << (3 * j);
    }

    // one2one for k = r (own column position)
    const int m1r = (m1p >> (3 * r)) & 7;       // match1[r]
    const int m1j = (m1p >> (3 * m2o)) & 7;     // match1[match2[r]]
    const bool o2o = (m1j == r) && (m1r < en) && (m2o < tn);

    // scatter fold over k=0..7 ascending (last-wins == numpy fancy assign):
    // row m1[k] takes true row m2[k]
    const int contrib = o2o ? ((8 | m2o) << (4 * m1r)) : 0;
    const int cmask   = o2o ? (0xF      << (4 * m1r)) : 0;
    int wrd = 0;
#pragma unroll
    for (int s = 0; s < 8; s++) {
        const int cw = __shfl(contrib, s, 8);
        const int cm = __shfl(cmask,  s, 8);
        wrd = (wrd & ~cm) | cw;
    }

    // this lane's output row r: source true row j if matched
    const int  v = (wrd >> (4 * r)) & 15;
    const bool matched = (v & 8) != 0;
    const int  j = v & 7;

    float o0=0,o1=0,o2=0,o3=0,o4=0,o5=0,o6=0,o7=0,o8=0,o9=0,o10=0;
    if (matched) {                      // ~44% lanes; 3 wide loads
        const int sr = gt * 8 + j;
        const float2 p  = tl2[sr];      // unmasked true loc
        const float4 f0 = tf4[2 * sr];
        const float4 f1 = tf4[2 * sr + 1];
        o0 = p.x;  o1 = p.y;
        o2 = f0.x; o3 = f0.y; o4 = f0.z; o5 = f0.w;
        o6 = f1.x; o7 = f1.y; o8 = f1.z; o9 = f1.w;
        o10 = 1.0f;                     // o2o implies j < tn
    }
    {
        float* row = sw + tloc * 88 + r * 11;
        row[0]=o0; row[1]=o1; row[2]=o2; row[3]=o3; row[4]=o4; row[5]=o5;
        row[6]=o6; row[7]=o7; row[8]=o8; row[9]=o9; row[10]=o10;
    }
    __syncthreads();

    // wave's LDS region is CONTIGUOUS and equals the output layout:
    // 8 tiles * 22 float4 = 176 float4 -> 3 coalesced dwordx4 stores.
    const float4* sw4 = (const float4*)sw;
    float4* ob = out4 + (size_t)tb * 22;
#pragma unroll
    for (int k = 0; k < 3; k++) {
        const int fidx = L + 64 * k;
        if (fidx < 176) ob[fidx] = sw4[fidx];
    }
}

extern "C" void kernel_launch(void* const* d_in, const int* in_sizes, int n_in,
                              void* d_out, int out_size, void* d_ws, size_t ws_size,
                              hipStream_t stream) {
    const float* est_locs    = (const float*)d_in[0];
    const float* true_locs   = (const float*)d_in[1];
    const float* true_fluxes = (const float*)d_in[2];
    const int*   est_n       = (const int*)d_in[3];
    const int*   true_n      = (const int*)d_in[4];
    float* out = (float*)d_out;

    mvd_coop<<<TT / 32, 256, 0, stream>>>(
        (const float2*)est_locs, (const float2*)true_locs,
        (const float4*)true_fluxes, est_n, true_n, (float4*)out);
}